// Round 4
// baseline (336.134 us; speedup 1.0000x reference)
//
#include <hip/hip_runtime.h>
#include <hip/hip_cooperative_groups.h>
#include <math.h>

namespace cg = cooperative_groups;

#define NN 8192
#define KDIM 512
#define DD 256
#define CS 32    // prefix chunk size
#define NC 256   // number of chunks == grid size of coop kernel

typedef float4 f4;
typedef __attribute__((ext_vector_type(4))) float f4v;  // native vec for nontemporal

// ---------- K1: H = X @ W (f32 vector GEMM, 64x64 tile, BK=32) ----------
__global__ __launch_bounds__(256) void k_gemm(const float* __restrict__ X,
                                              const float* __restrict__ W,
                                              float* __restrict__ H) {
  __shared__ float Xs[32][64];  // [k][r] (transposed)
  __shared__ float Ws[32][64];  // [k][c]
  const int tid = threadIdx.x;
  const int tx = tid & 15;   // col group -> 4 cols
  const int ty = tid >> 4;   // row group -> 4 rows
  const int r0 = blockIdx.x * 64;
  const int c0 = blockIdx.y * 64;
  float acc[4][4] = {};
  for (int k0 = 0; k0 < KDIM; k0 += 32) {
#pragma unroll
    for (int q = 0; q < 2; ++q) {
      int fi = tid + q * 256;       // 0..511 float4 units of X tile (64 rows x 8 f4)
      int r = fi >> 3;
      int kq = fi & 7;
      f4 v = *reinterpret_cast<const f4*>(&X[(size_t)(r0 + r) * KDIM + k0 + kq * 4]);
      Xs[kq * 4 + 0][r] = v.x; Xs[kq * 4 + 1][r] = v.y;
      Xs[kq * 4 + 2][r] = v.z; Xs[kq * 4 + 3][r] = v.w;
    }
#pragma unroll
    for (int q = 0; q < 2; ++q) {
      int fi = tid + q * 256;       // 0..511 float4 units of W tile (32 k x 16 f4)
      int k = fi >> 4;
      int cq = fi & 15;
      f4 v = *reinterpret_cast<const f4*>(&W[(size_t)(k0 + k) * DD + c0 + cq * 4]);
      *reinterpret_cast<f4*>(&Ws[k][cq * 4]) = v;
    }
    __syncthreads();
#pragma unroll
    for (int k = 0; k < 32; ++k) {
      f4 xv = *reinterpret_cast<const f4*>(&Xs[k][ty * 4]);
      f4 wv = *reinterpret_cast<const f4*>(&Ws[k][tx * 4]);
      float xs[4] = {xv.x, xv.y, xv.z, xv.w};
      float ws[4] = {wv.x, wv.y, wv.z, wv.w};
#pragma unroll
      for (int i = 0; i < 4; ++i)
#pragma unroll
        for (int j = 0; j < 4; ++j) acc[i][j] += xs[i] * ws[j];
    }
    __syncthreads();
  }
#pragma unroll
  for (int i = 0; i < 4; ++i) {
    f4 v = {acc[i][0], acc[i][1], acc[i][2], acc[i][3]};
    *reinterpret_cast<f4*>(&H[(size_t)(r0 + ty * 4 + i) * DD + c0 + tx * 4]) = v;
  }
}

// ---------- K2 (cooperative): rowdots -> tmax/coef/rank -> chunk -> prefix -> finalize
__global__ __launch_bounds__(256) void k_coop(const float* __restrict__ av,
                                              float* __restrict__ out,
                                              float* __restrict__ Ab,
                                              float* __restrict__ wsp) {
  // pointer map (must match kernel_launch)
  float* s  = wsp + 0 * NN;
  float* t  = wsp + 1 * NN;
  float* E1 = wsp + 2 * NN;
  float* E2 = wsp + 3 * NN;
  float* c1 = wsp + 4 * NN;
  float* c2 = wsp + 5 * NN;
  float* f1 = wsp + 6 * NN;
  float* f2 = wsp + 7 * NN;
  float* H     = out;
  float* PRE1  = Ab;
  float* PRE2  = Ab + 4194304;
  float* Ctot1 = Ab + 8388608;
  float* Ctot2 = Ctot1 + NC * DD;
  float* cs1   = Ctot2 + NC * DD;
  float* cs2   = cs1 + NC;
  float* p1s   = cs2 + NC;            // NN+1
  float* p2s   = p1s + (NN + 256);    // NN+1
  float* tsort = p2s + (NN + 256);    // NN
  int*   perm  = (int*)(tsort + NN);  // NN

  __shared__ float ts[NN];        // 32 KB: t (phase B) then tsort (phase E)
  __shared__ float sa[NC], sb[NC];
  __shared__ float lred[4];

  cg::grid_group grid = cg::this_grid();
  const int b = blockIdx.x;
  const int tid = threadIdx.x;
  const int wid = tid >> 6, lane = tid & 63;

  // ---- phase A: rowdots (rows b*32 .. b*32+31) ----
  {
    f4 a1 = *reinterpret_cast<const f4*>(&av[lane * 4]);
    f4 a2 = *reinterpret_cast<const f4*>(&av[DD + lane * 4]);
#pragma unroll
    for (int it = 0; it < 8; ++it) {
      int i = b * 32 + it * 4 + wid;
      f4 h = *reinterpret_cast<const f4*>(&H[(size_t)i * DD + lane * 4]);
      float p1 = h.x * a1.x + h.y * a1.y + h.z * a1.z + h.w * a1.w;
      float p2 = h.x * a2.x + h.y * a2.y + h.z * a2.z + h.w * a2.w;
      for (int off = 32; off > 0; off >>= 1) {
        p1 += __shfl_down(p1, off);
        p2 += __shfl_down(p2, off);
      }
      if (lane == 0) {
        s[i] = p1;
        t[i] = p2;
        E1[i] = expf(p2);
        E2[i] = expf(0.2f * p2);
      }
    }
  }
  grid.sync();

  // ---- phase B: stage t in LDS, tmax, c1/c2, direct rank+scatter ----
  for (int k = tid; k < NN; k += 256) ts[k] = t[k];
  __syncthreads();
  {
    float m = -1e30f;
    for (int k = tid; k < NN; k += 256) m = fmaxf(m, ts[k]);
    for (int off = 32; off > 0; off >>= 1) m = fmaxf(m, __shfl_down(m, off));
    if (lane == 0) lred[wid] = m;
    __syncthreads();
    float tmax = fmaxf(fmaxf(lred[0], lred[1]), fmaxf(lred[2], lred[3]));
    if (tid < 32) {
      int i = b * 32 + tid;
      float si = s[i];
      float e = si + tmax;
      float mm = e > 0.f ? e : 0.2f * e;
      c1[i] = expf(si - mm);
      c2[i] = expf(0.2f * si - mm);
    }
    // rank: wave `wid` owns keys j = b*32 + wid*8 + q, q=0..7
    float tkv[8]; int jj[8]; int cnt[8];
#pragma unroll
    for (int q = 0; q < 8; ++q) {
      jj[q] = b * 32 + wid * 8 + q;
      tkv[q] = ts[jj[q]];
      cnt[q] = 0;
    }
    for (int m2 = 0; m2 < NN / 64; ++m2) {
      int i = lane + m2 * 64;
      float v = ts[i];
#pragma unroll
      for (int q = 0; q < 8; ++q)
        cnt[q] += (v < tkv[q]) || (v == tkv[q] && i < jj[q]);
    }
#pragma unroll
    for (int q = 0; q < 8; ++q) {
      int c = cnt[q];
      for (int off = 32; off > 0; off >>= 1) c += __shfl_down(c, off);
      if (lane == 0) { tsort[c] = tkv[q]; perm[c] = jj[q]; }
    }
  }
  grid.sync();

  // ---- phase C: chunk totals (chunk b) ----
  {
    int d = tid;
    float s1 = 0.f, s2 = 0.f, aa1 = 0.f, aa2 = 0.f;
    for (int kk = 0; kk < CS; ++kk) {
      int p = perm[b * CS + kk];
      float e1 = E1[p], e2 = E2[p];
      float h = H[(size_t)p * DD + d];
      s1 += e1 * h; s2 += e2 * h;
      aa1 += e1;    aa2 += e2;
    }
    Ctot1[b * DD + d] = s1;
    Ctot2[b * DD + d] = s2;
    if (d == 0) { cs1[b] = aa1; cs2[b] = aa2; }
  }
  grid.sync();

  // ---- phase D: prefix arrays PRE1/PRE2 + scalar p1s/p2s ----
  {
    int d = tid;
    float r1 = 0.f, r2 = 0.f;
    for (int cc = 0; cc < b; ++cc) {
      r1 += Ctot1[cc * DD + d];
      r2 += Ctot2[cc * DD + d];
    }
    sa[d] = (d < b) ? cs1[d] : 0.f;
    sb[d] = (d < b) ? cs2[d] : 0.f;
    __syncthreads();
    for (int off = 128; off > 0; off >>= 1) {
      if (d < off) { sa[d] += sa[d + off]; sb[d] += sb[d + off]; }
      __syncthreads();
    }
    float sr1 = sa[0], sr2 = sb[0];
    for (int kk = 0; kk < CS; ++kk) {
      int k = b * CS + kk;
      int p = perm[k];
      PRE1[(size_t)k * DD + d] = r1;
      PRE2[(size_t)k * DD + d] = r2;
      float e1 = E1[p], e2 = E2[p];
      float h = H[(size_t)p * DD + d];
      r1 += e1 * h; r2 += e2 * h;
      if (d == 0) { p1s[k] = sr1; p2s[k] = sr2; sr1 += e1; sr2 += e2; }
    }
    if (b == NC - 1) {
      PRE1[(size_t)NN * DD + d] = r1;
      PRE2[(size_t)NN * DD + d] = r2;
      if (d == 0) { p1s[NN] = sr1; p2s[NN] = sr2; }
    }
  }
  grid.sync();

  // ---- phase E: finalize rows b*32 .. b*32+31 (overwrites H rows with out) ----
  for (int k = tid; k < NN; k += 256) ts[k] = tsort[k];
  __syncthreads();
#pragma unroll
  for (int it = 0; it < 8; ++it) {
    int i = b * 32 + it * 4 + wid;
    float key = -s[i];
    int lo = 0, hi = NN;  // count of tsort <= key (wave-uniform LDS broadcast)
    while (lo < hi) {
      int mid = (lo + hi) >> 1;
      if (ts[mid] <= key) lo = mid + 1; else hi = mid;
    }
    int k = lo;
    float cc1 = c1[i], cc2 = c2[i];
    float Z = cc1 * (p1s[NN] - p1s[k]) + cc2 * p2s[k];
    float rZ = 1.0f / Z;
    if (lane == 0) { f1[i] = rZ * cc1; f2[i] = rZ * cc2; }
    int d = lane * 4;
    f4 P1 = *reinterpret_cast<const f4*>(&PRE1[(size_t)k * DD + d]);
    f4 P2 = *reinterpret_cast<const f4*>(&PRE2[(size_t)k * DD + d]);
    f4 T1 = *reinterpret_cast<const f4*>(&PRE1[(size_t)NN * DD + d]);
    f4 o;
    o.x = rZ * (cc1 * (T1.x - P1.x) + cc2 * P2.x);
    o.y = rZ * (cc1 * (T1.y - P1.y) + cc2 * P2.y);
    o.z = rZ * (cc1 * (T1.z - P1.z) + cc2 * P2.z);
    o.w = rZ * (cc1 * (T1.w - P1.w) + cc2 * P2.w);
    *reinterpret_cast<f4*>(&out[(size_t)i * DD + d]) = o;
  }
}

// ---------- K3: stream A = (s_i + t_j > 0) ? f1_i*E1_j : f2_i*E2_j ----------
__global__ __launch_bounds__(256) void k_astream(const float* __restrict__ s,
                                                 const float* __restrict__ t,
                                                 const float* __restrict__ E1,
                                                 const float* __restrict__ E2,
                                                 const float* __restrict__ f1,
                                                 const float* __restrict__ f2,
                                                 float* __restrict__ A) {
  int j0 = blockIdx.x * 1024 + threadIdx.x * 4;
  int i0 = blockIdx.y * 32;
  f4 t4  = *reinterpret_cast<const f4*>(&t[j0]);
  f4 e14 = *reinterpret_cast<const f4*>(&E1[j0]);
  f4 e24 = *reinterpret_cast<const f4*>(&E2[j0]);
#pragma unroll 4
  for (int rr = 0; rr < 32; ++rr) {
    int i = i0 + rr;
    float ss = s[i], ff1 = f1[i], ff2 = f2[i];
    f4v o;
    float e;
    e = ss + t4.x; o.x = (e > 0.f) ? ff1 * e14.x : ff2 * e24.x;
    e = ss + t4.y; o.y = (e > 0.f) ? ff1 * e14.y : ff2 * e24.y;
    e = ss + t4.z; o.z = (e > 0.f) ? ff1 * e14.z : ff2 * e24.z;
    e = ss + t4.w; o.w = (e > 0.f) ? ff1 * e14.w : ff2 * e24.w;
    __builtin_nontemporal_store(o, reinterpret_cast<f4v*>(&A[(size_t)i * NN + j0]));
  }
}

extern "C" void kernel_launch(void* const* d_in, const int* in_sizes, int n_in,
                              void* d_out, int out_size, void* d_ws, size_t ws_size,
                              hipStream_t stream) {
  const float* X  = (const float*)d_in[0];
  const float* W  = (const float*)d_in[1];
  const float* av = (const float*)d_in[2];
  float* outp = (float*)d_out;                  // [NN*DD]
  float* Ap   = outp + (size_t)NN * DD;         // [NN*NN]
  float* wsp  = (float*)d_ws;

  // ws vector map (mirrored in k_coop)
  float* s  = wsp + 0 * NN;
  float* t  = wsp + 1 * NN;
  float* E1 = wsp + 2 * NN;
  float* E2 = wsp + 3 * NN;
  float* f1 = wsp + 6 * NN;
  float* f2 = wsp + 7 * NN;

  float* H = outp;  // H lives in out-region until phase E overwrites it

  k_gemm<<<dim3(NN / 64, DD / 64), 256, 0, stream>>>(X, W, H);

  void* cargs[] = {(void*)&av, (void*)&outp, (void*)&Ap, (void*)&wsp};
  hipLaunchCooperativeKernel((void*)k_coop, dim3(NC), dim3(256), cargs, 0, stream);

  k_astream<<<dim3(NN / 1024, NN / 32), 256, 0, stream>>>(s, t, E1, E2, f1, f2, Ap);
}

// Round 5
// 196.543 us; speedup vs baseline: 1.7102x; 1.7102x over previous
//
#include <hip/hip_runtime.h>
#include <math.h>

#define NN 8192
#define KDIM 512
#define DD 256
#define CS 32    // prefix chunk size
#define NC 256   // number of chunks

typedef float4 f4;
typedef __attribute__((ext_vector_type(4))) float f4v;  // native vec for nontemporal

__device__ __forceinline__ float dot4(const f4& x, const f4& y) {
  return x.x * y.x + x.y * y.y + x.z * y.z + x.w * y.w;
}

// ---------- K1: H = X @ W (f32 vector GEMM, 64x64 tile, BK=32) ----------
// by==0 blocks additionally compute w1 = W@a1, w2 = W@a2 (redundantly) and
// then s = X@w1, t = X@w2 for their 64 rows (== H@a1, H@a2 up to fp order).
__global__ __launch_bounds__(256) void k_gemm(const float* __restrict__ X,
                                              const float* __restrict__ W,
                                              const float* __restrict__ av,
                                              float* __restrict__ H,
                                              float* __restrict__ s,
                                              float* __restrict__ t) {
  __shared__ float Xs[32][64];  // [k][r] (transposed); reused as wv1/wv2 after
  __shared__ float Ws[32][64];  // [k][c]
  const int tid = threadIdx.x;
  const int tx = tid & 15;   // col group -> 4 cols
  const int ty = tid >> 4;   // row group -> 4 rows
  const int r0 = blockIdx.x * 64;
  const int c0 = blockIdx.y * 64;
  float acc[4][4] = {};
  for (int k0 = 0; k0 < KDIM; k0 += 32) {
#pragma unroll
    for (int q = 0; q < 2; ++q) {
      int fi = tid + q * 256;       // 0..511 float4 units of X tile (64 rows x 8 f4)
      int r = fi >> 3;
      int kq = fi & 7;
      f4 v = *reinterpret_cast<const f4*>(&X[(size_t)(r0 + r) * KDIM + k0 + kq * 4]);
      Xs[kq * 4 + 0][r] = v.x; Xs[kq * 4 + 1][r] = v.y;
      Xs[kq * 4 + 2][r] = v.z; Xs[kq * 4 + 3][r] = v.w;
    }
#pragma unroll
    for (int q = 0; q < 2; ++q) {
      int fi = tid + q * 256;       // 0..511 float4 units of W tile (32 k x 16 f4)
      int k = fi >> 4;
      int cq = fi & 15;
      f4 v = *reinterpret_cast<const f4*>(&W[(size_t)(k0 + k) * DD + c0 + cq * 4]);
      *reinterpret_cast<f4*>(&Ws[k][cq * 4]) = v;
    }
    __syncthreads();
#pragma unroll
    for (int k = 0; k < 32; ++k) {
      f4 xv = *reinterpret_cast<const f4*>(&Xs[k][ty * 4]);
      f4 wv = *reinterpret_cast<const f4*>(&Ws[k][tx * 4]);
      float xs[4] = {xv.x, xv.y, xv.z, xv.w};
      float ws[4] = {wv.x, wv.y, wv.z, wv.w};
#pragma unroll
      for (int i = 0; i < 4; ++i)
#pragma unroll
        for (int j = 0; j < 4; ++j) acc[i][j] += xs[i] * ws[j];
    }
    __syncthreads();
  }
#pragma unroll
  for (int i = 0; i < 4; ++i) {
    f4 v = {acc[i][0], acc[i][1], acc[i][2], acc[i][3]};
    *reinterpret_cast<f4*>(&H[(size_t)(r0 + ty * 4 + i) * DD + c0 + tx * 4]) = v;
  }

  if (c0 == 0) {
    // reuse Xs storage for the two 512-long w-vectors
    float* wv1 = &Xs[0][0];        // [512]
    float* wv2 = &Xs[0][0] + 512;  // [512]
    // w-vec: thread handles k = tid, tid+256
    for (int k = tid; k < KDIM; k += 256) {
      float acc1 = 0.f, acc2 = 0.f;
#pragma unroll 8
      for (int d4 = 0; d4 < DD / 4; ++d4) {
        f4 wrow = *reinterpret_cast<const f4*>(&W[(size_t)k * DD + d4 * 4]);
        f4 a1v = *reinterpret_cast<const f4*>(&av[d4 * 4]);
        f4 a2v = *reinterpret_cast<const f4*>(&av[DD + d4 * 4]);
        acc1 += dot4(wrow, a1v);
        acc2 += dot4(wrow, a2v);
      }
      wv1[k] = acc1;
      wv2[k] = acc2;
    }
    __syncthreads();
    // s,t for rows r0..r0+63: wave wid -> 16 rows; lane l -> cols l*8..l*8+7
    int wid = tid >> 6, lane = tid & 63;
    f4 w1a = *reinterpret_cast<const f4*>(&wv1[lane * 8]);
    f4 w1b = *reinterpret_cast<const f4*>(&wv1[lane * 8 + 4]);
    f4 w2a = *reinterpret_cast<const f4*>(&wv2[lane * 8]);
    f4 w2b = *reinterpret_cast<const f4*>(&wv2[lane * 8 + 4]);
    for (int rr = 0; rr < 16; ++rr) {
      int i = r0 + wid * 16 + rr;
      f4 xa = *reinterpret_cast<const f4*>(&X[(size_t)i * KDIM + lane * 8]);
      f4 xb = *reinterpret_cast<const f4*>(&X[(size_t)i * KDIM + lane * 8 + 4]);
      float p1 = dot4(xa, w1a) + dot4(xb, w1b);
      float p2 = dot4(xa, w2a) + dot4(xb, w2b);
      for (int off = 32; off > 0; off >>= 1) {
        p1 += __shfl_down(p1, off);
        p2 += __shfl_down(p2, off);
      }
      if (lane == 0) { s[i] = p1; t[i] = p2; }
    }
  }
}

// ---------- K2: per block: tmax (redundant), E1/E2 + c1/c2 (own rows),
//                rank+scatter (own 32 keys) ----------
__global__ __launch_bounds__(256) void k_mid(const float* __restrict__ s,
                                             const float* __restrict__ t,
                                             float* __restrict__ E1,
                                             float* __restrict__ E2,
                                             float* __restrict__ c1,
                                             float* __restrict__ c2,
                                             float* __restrict__ tsort,
                                             int* __restrict__ perm) {
  __shared__ float ts[NN];   // 32 KB
  __shared__ float lred[4];
  const int b = blockIdx.x;
  const int tid = threadIdx.x;
  const int wid = tid >> 6, lane = tid & 63;

  // stage t into LDS, tracking running max
  float m = -1e30f;
#pragma unroll
  for (int q = 0; q < NN / 1024; ++q) {
    int idx = (q * 256 + tid) * 4;
    f4 v = *reinterpret_cast<const f4*>(&t[idx]);
    *reinterpret_cast<f4*>(&ts[idx]) = v;
    m = fmaxf(m, fmaxf(fmaxf(v.x, v.y), fmaxf(v.z, v.w)));
  }
  for (int off = 32; off > 0; off >>= 1) m = fmaxf(m, __shfl_down(m, off));
  if (lane == 0) lred[wid] = m;
  __syncthreads();
  float tmax = fmaxf(fmaxf(lred[0], lred[1]), fmaxf(lred[2], lred[3]));

  // own rows: exps and coefficients
  if (tid < 32) {
    int i = b * 32 + tid;
    float ti = ts[i];
    E1[i] = expf(ti);
    E2[i] = expf(0.2f * ti);
    float si = s[i];
    float e = si + tmax;
    float mm = e > 0.f ? e : 0.2f * e;
    c1[i] = expf(si - mm);
    c2[i] = expf(0.2f * si - mm);
  }

  // rank own 32 keys: wave wid owns keys j = b*32 + wid*8 + q
  float tkv[8]; int jj[8]; int cnt[8];
#pragma unroll
  for (int q = 0; q < 8; ++q) {
    jj[q] = b * 32 + wid * 8 + q;
    tkv[q] = ts[jj[q]];
    cnt[q] = 0;
  }
  for (int m2 = 0; m2 < NN / 64; ++m2) {
    int i = lane + m2 * 64;
    float v = ts[i];
#pragma unroll
    for (int q = 0; q < 8; ++q)
      cnt[q] += (v < tkv[q]) || (v == tkv[q] && i < jj[q]);
  }
#pragma unroll
  for (int q = 0; q < 8; ++q) {
    int c = cnt[q];
    for (int off = 32; off > 0; off >>= 1) c += __shfl_down(c, off);
    if (lane == 0) { tsort[c] = tkv[q]; perm[c] = jj[q]; }
  }
}

// ---------- K3: per-chunk totals of E1*H and E2*H over sorted order ----------
__global__ __launch_bounds__(256) void k_chunk(const float* __restrict__ H,
                                               const float* __restrict__ E1,
                                               const float* __restrict__ E2,
                                               const int* __restrict__ perm,
                                               float* __restrict__ Ctot1,
                                               float* __restrict__ Ctot2,
                                               float* __restrict__ cs1,
                                               float* __restrict__ cs2) {
  __shared__ int pms[CS];
  __shared__ float pe1[CS], pe2[CS];
  int c = blockIdx.x;
  int d = threadIdx.x;
  if (d < CS) {
    int p = perm[c * CS + d];
    pms[d] = p;
    pe1[d] = E1[p];
    pe2[d] = E2[p];
  }
  __syncthreads();
  float s1 = 0.f, s2 = 0.f, a1 = 0.f, a2 = 0.f;
#pragma unroll 4
  for (int kk = 0; kk < CS; ++kk) {
    float e1 = pe1[kk], e2 = pe2[kk];
    float h = H[(size_t)pms[kk] * DD + d];
    s1 += e1 * h; s2 += e2 * h;
    a1 += e1;     a2 += e2;
  }
  Ctot1[c * DD + d] = s1;
  Ctot2[c * DD + d] = s2;
  if (d == 0) { cs1[c] = a1; cs2[c] = a2; }
}

// ---------- K4: exclusive prefix arrays PRE1/PRE2 (+ scalar p1s/p2s) ----------
__global__ __launch_bounds__(256) void k_prefix(const float* __restrict__ H,
                                                const float* __restrict__ E1,
                                                const float* __restrict__ E2,
                                                const int* __restrict__ perm,
                                                const float* __restrict__ Ctot1,
                                                const float* __restrict__ Ctot2,
                                                const float* __restrict__ cs1,
                                                const float* __restrict__ cs2,
                                                float* __restrict__ PRE1,
                                                float* __restrict__ PRE2,
                                                float* __restrict__ p1s,
                                                float* __restrict__ p2s) {
  __shared__ float sa[NC], sb[NC];
  __shared__ int pms[CS];
  __shared__ float pe1[CS], pe2[CS];
  int c = blockIdx.x;
  int d = threadIdx.x;
  if (d < CS) {
    int p = perm[c * CS + d];
    pms[d] = p;
    pe1[d] = E1[p];
    pe2[d] = E2[p];
  }
  // chunk-offset for this d: sum of Ctot[0..c-1][d], pipelined (split accumulators)
  float r1a = 0.f, r1b = 0.f, r2a = 0.f, r2b = 0.f;
  int cc = 0;
  for (; cc + 4 <= c; cc += 4) {
    r1a += Ctot1[(cc + 0) * DD + d];
    r1b += Ctot1[(cc + 1) * DD + d];
    r1a += Ctot1[(cc + 2) * DD + d];
    r1b += Ctot1[(cc + 3) * DD + d];
    r2a += Ctot2[(cc + 0) * DD + d];
    r2b += Ctot2[(cc + 1) * DD + d];
    r2a += Ctot2[(cc + 2) * DD + d];
    r2b += Ctot2[(cc + 3) * DD + d];
  }
  for (; cc < c; ++cc) {
    r1a += Ctot1[cc * DD + d];
    r2a += Ctot2[cc * DD + d];
  }
  float r1 = r1a + r1b, r2 = r2a + r2b;
  // scalar prefix of cs over chunks < c via LDS tree reduction
  sa[d] = (d < c) ? cs1[d] : 0.f;
  sb[d] = (d < c) ? cs2[d] : 0.f;
  __syncthreads();
  for (int off = 128; off > 0; off >>= 1) {
    if (d < off) { sa[d] += sa[d + off]; sb[d] += sb[d + off]; }
    __syncthreads();
  }
  float sr1 = sa[0], sr2 = sb[0];
#pragma unroll 2
  for (int kk = 0; kk < CS; ++kk) {
    int k = c * CS + kk;
    PRE1[(size_t)k * DD + d] = r1;
    PRE2[(size_t)k * DD + d] = r2;
    float e1 = pe1[kk], e2 = pe2[kk];
    float h = H[(size_t)pms[kk] * DD + d];
    r1 += e1 * h; r2 += e2 * h;
    if (d == 0) { p1s[k] = sr1; p2s[k] = sr2; sr1 += e1; sr2 += e2; }
  }
  if (c == NC - 1) {
    PRE1[(size_t)NN * DD + d] = r1;
    PRE2[(size_t)NN * DD + d] = r2;
    if (d == 0) { p1s[NN] = sr1; p2s[NN] = sr2; }
  }
}

// ---------- K5: per-row finalize: k_i (batched binary search), Z, f1/f2, out ----------
__global__ __launch_bounds__(256) void k_finalize(const float* __restrict__ s,
                                                  const float* __restrict__ c1,
                                                  const float* __restrict__ c2,
                                                  const float* __restrict__ tsort,
                                                  const float* __restrict__ p1s,
                                                  const float* __restrict__ p2s,
                                                  const float* __restrict__ PRE1,
                                                  const float* __restrict__ PRE2,
                                                  float* __restrict__ out,
                                                  float* __restrict__ f1,
                                                  float* __restrict__ f2) {
  __shared__ float ts[NN];  // staged tsort
  int b = blockIdx.x;
  int tid = threadIdx.x;
  int wid = tid >> 6, lane = tid & 63;
#pragma unroll
  for (int q = 0; q < NN / 1024; ++q) {
    int idx = (q * 256 + tid) * 4;
    *reinterpret_cast<f4*>(&ts[idx]) = *reinterpret_cast<const f4*>(&tsort[idx]);
  }
  __syncthreads();
  // batched searches: 8 independent chains
  int kk[8];
#pragma unroll
  for (int it = 0; it < 8; ++it) {
    int i = b * 32 + it * 4 + wid;
    float key = -s[i];
    int lo = 0, hi = NN;
    while (lo < hi) {
      int mid = (lo + hi) >> 1;
      if (ts[mid] <= key) lo = mid + 1; else hi = mid;
    }
    kk[it] = lo;
  }
  int d = lane * 4;
  f4 T1 = *reinterpret_cast<const f4*>(&PRE1[(size_t)NN * DD + d]);
  float tot1 = p1s[NN];
#pragma unroll
  for (int it = 0; it < 8; ++it) {
    int i = b * 32 + it * 4 + wid;
    int k = kk[it];
    float cc1 = c1[i], cc2 = c2[i];
    float Z = cc1 * (tot1 - p1s[k]) + cc2 * p2s[k];
    float rZ = 1.0f / Z;
    if (lane == 0) { f1[i] = rZ * cc1; f2[i] = rZ * cc2; }
    f4 P1 = *reinterpret_cast<const f4*>(&PRE1[(size_t)k * DD + d]);
    f4 P2 = *reinterpret_cast<const f4*>(&PRE2[(size_t)k * DD + d]);
    f4 o;
    o.x = rZ * (cc1 * (T1.x - P1.x) + cc2 * P2.x);
    o.y = rZ * (cc1 * (T1.y - P1.y) + cc2 * P2.y);
    o.z = rZ * (cc1 * (T1.z - P1.z) + cc2 * P2.z);
    o.w = rZ * (cc1 * (T1.w - P1.w) + cc2 * P2.w);
    *reinterpret_cast<f4*>(&out[(size_t)i * DD + d]) = o;
  }
}

// ---------- K6: stream A = (s_i + t_j > 0) ? f1_i*E1_j : f2_i*E2_j ----------
__global__ __launch_bounds__(256) void k_astream(const float* __restrict__ s,
                                                 const float* __restrict__ t,
                                                 const float* __restrict__ E1,
                                                 const float* __restrict__ E2,
                                                 const float* __restrict__ f1,
                                                 const float* __restrict__ f2,
                                                 float* __restrict__ A) {
  int j0 = blockIdx.x * 1024 + threadIdx.x * 4;
  int i0 = blockIdx.y * 32;
  f4 t4  = *reinterpret_cast<const f4*>(&t[j0]);
  f4 e14 = *reinterpret_cast<const f4*>(&E1[j0]);
  f4 e24 = *reinterpret_cast<const f4*>(&E2[j0]);
#pragma unroll 4
  for (int rr = 0; rr < 32; ++rr) {
    int i = i0 + rr;
    float ss = s[i], ff1 = f1[i], ff2 = f2[i];
    f4v o;
    float e;
    e = ss + t4.x; o.x = (e > 0.f) ? ff1 * e14.x : ff2 * e24.x;
    e = ss + t4.y; o.y = (e > 0.f) ? ff1 * e14.y : ff2 * e24.y;
    e = ss + t4.z; o.z = (e > 0.f) ? ff1 * e14.z : ff2 * e24.z;
    e = ss + t4.w; o.w = (e > 0.f) ? ff1 * e14.w : ff2 * e24.w;
    __builtin_nontemporal_store(o, reinterpret_cast<f4v*>(&A[(size_t)i * NN + j0]));
  }
}

extern "C" void kernel_launch(void* const* d_in, const int* in_sizes, int n_in,
                              void* d_out, int out_size, void* d_ws, size_t ws_size,
                              hipStream_t stream) {
  const float* X  = (const float*)d_in[0];
  const float* W  = (const float*)d_in[1];
  const float* av = (const float*)d_in[2];
  float* outp = (float*)d_out;                  // [NN*DD]
  float* A = outp + (size_t)NN * DD;            // [NN*NN]

  // small vectors in ws (256 KB)
  float* wsp = (float*)d_ws;
  float* s  = wsp + 0 * NN;
  float* t  = wsp + 1 * NN;
  float* E1 = wsp + 2 * NN;
  float* E2 = wsp + 3 * NN;
  float* c1 = wsp + 4 * NN;
  float* c2 = wsp + 5 * NN;
  float* f1 = wsp + 6 * NN;
  float* f2 = wsp + 7 * NN;

  // big scratch inside the A-region of d_out (consumed before k_astream overwrites it)
  float* H     = outp;                // H in out-region; overwritten by k_finalize
  float* PRE1  = A;                   // 8193*256
  float* PRE2  = A + 4194304;         // 8193*256
  float* Ctot1 = A + 8388608;         // NC*DD
  float* Ctot2 = Ctot1 + NC * DD;
  float* cs1   = Ctot2 + NC * DD;
  float* cs2   = cs1 + NC;
  float* p1s   = cs2 + NC;            // NN+1
  float* p2s   = p1s + (NN + 256);    // NN+1
  float* tsort = p2s + (NN + 256);    // NN
  int*   perm  = (int*)(tsort + NN);  // NN

  k_gemm<<<dim3(NN / 64, DD / 64), 256, 0, stream>>>(X, W, av, H, s, t);
  k_mid<<<NC, 256, 0, stream>>>(s, t, E1, E2, c1, c2, tsort, perm);
  k_chunk<<<NC, 256, 0, stream>>>(H, E1, E2, perm, Ctot1, Ctot2, cs1, cs2);
  k_prefix<<<NC, 256, 0, stream>>>(H, E1, E2, perm, Ctot1, Ctot2, cs1, cs2,
                                   PRE1, PRE2, p1s, p2s);
  k_finalize<<<NN / 32, 256, 0, stream>>>(s, c1, c2, tsort, p1s, p2s, PRE1, PRE2,
                                          outp, f1, f2);
  k_astream<<<dim3(NN / 1024, NN / 32), 256, 0, stream>>>(s, t, E1, E2, f1, f2, A);
}